// Round 1
// baseline (360.486 us; speedup 1.0000x reference)
//
#include <hip/hip_runtime.h>
#include <math.h>

#define IMG   224
#define POOL1 110     // maxpooled conv1 map: 110x110
#define NB    128

// ---------------------------------------------------------------------------
// Kernel 1: conv1(3->6,5x5,VALID) + maxpool2x2 fused, then partial
// shifted-window sums into S[b][6][5][5] (for the conv2+global-mean collapse).
// Block = 16x16 pooled outputs for one (b, tile). 7x7 tiles cover 110x110.
// ---------------------------------------------------------------------------
__global__ __launch_bounds__(256) void k1_conv1(
    const float* __restrict__ x, const float* __restrict__ w1,
    const float* __restrict__ b1, float* __restrict__ S)
{
  const int tid = threadIdx.x;
  const int tile = blockIdx.x;          // 0..48
  const int b = blockIdx.y;
  const int t_y = tile / 7, t_x = tile % 7;
  const int P0y = t_y * 16, P0x = t_x * 16;
  const int ty = tid >> 4, tx = tid & 15;
  const int py = P0y + ty, px = P0x + tx;   // pooled coords

  __shared__ float in_t[3][36][37];     // +1 pad on inner dim
  __shared__ float rp[16][6][5];        // row partials for S reduction

  // stage input region rows [2*P0y, 2*P0y+35], cols [2*P0x, 2*P0x+35]
  const int by = 2 * P0y, bx = 2 * P0x;
  for (int idx = tid; idx < 3 * 36 * 36; idx += 256) {
    int c = idx / 1296, r = idx % 1296;
    int row = r / 36, col = r % 36;
    int gy = by + row; if (gy > IMG - 1) gy = IMG - 1;   // clamp (unused lanes)
    int gx = bx + col; if (gx > IMG - 1) gx = IMG - 1;
    in_t[c][row][col] = x[((b * 3 + c) * IMG + gy) * IMG + gx];
  }
  __syncthreads();

  // conv: 2x2 conv positions (one maxpool window) x 6 output channels
  float acc[6][4];
  #pragma unroll
  for (int oc = 0; oc < 6; ++oc) {
    float bb = b1[oc];
    acc[oc][0] = bb; acc[oc][1] = bb; acc[oc][2] = bb; acc[oc][3] = bb;
  }
  #pragma unroll 1
  for (int c = 0; c < 3; ++c) {
    float v[6][6];
    #pragma unroll
    for (int i = 0; i < 6; ++i)
      #pragma unroll
      for (int j = 0; j < 6; ++j)
        v[i][j] = in_t[c][2 * ty + i][2 * tx + j];
    #pragma unroll
    for (int oc = 0; oc < 6; ++oc) {
      #pragma unroll
      for (int ky = 0; ky < 5; ++ky) {
        #pragma unroll
        for (int kx = 0; kx < 5; ++kx) {
          float w = w1[((oc * 3 + c) * 5 + ky) * 5 + kx];  // uniform -> s_load
          acc[oc][0] = fmaf(v[ky][kx],         w, acc[oc][0]);
          acc[oc][1] = fmaf(v[ky][kx + 1],     w, acc[oc][1]);
          acc[oc][2] = fmaf(v[ky + 1][kx],     w, acc[oc][2]);
          acc[oc][3] = fmaf(v[ky + 1][kx + 1], w, acc[oc][3]);
        }
      }
    }
  }

  const bool valid = (py < POOL1) && (px < POOL1);
  float z[6];
  #pragma unroll
  for (int oc = 0; oc < 6; ++oc) {
    float m = fmaxf(fmaxf(acc[oc][0], acc[oc][1]),
                    fmaxf(acc[oc][2], acc[oc][3]));
    z[oc] = valid ? m : 0.0f;
  }

  // Stage A: reduce over tx (16-lane segments) with kx window masks.
  // S[ic,ky,kx] = sum_{py in [ky,ky+105], px in [kx,kx+105]} z[ic,py,px]
  #pragma unroll
  for (int oc = 0; oc < 6; ++oc) {
    #pragma unroll
    for (int kx = 0; kx < 5; ++kx) {
      float vv = (px >= kx && px <= 105 + kx) ? z[oc] : 0.0f;
      vv += __shfl_xor(vv, 1, 16);
      vv += __shfl_xor(vv, 2, 16);
      vv += __shfl_xor(vv, 4, 16);
      vv += __shfl_xor(vv, 8, 16);
      if (tx == 0) rp[ty][oc][kx] = vv;
    }
  }
  __syncthreads();

  // Stage B: reduce over ty with ky masks, one atomicAdd per bin.
  if (tid < 150) {
    int oc = tid / 25, r = tid % 25, ky = r / 5, kx = r % 5;
    float s = 0.f;
    #pragma unroll
    for (int t = 0; t < 16; ++t) {
      int gpy = P0y + t;
      if (gpy >= ky && gpy <= 105 + ky) s += rp[t][oc][kx];
    }
    atomicAdd(&S[b * 150 + tid], s);
  }
}

// ---------------------------------------------------------------------------
// Kernel 2: conv2-as-dot-with-S + global mean + fc1/relu + fc2/sigmoid*2.
// One thread per batch element.
// ---------------------------------------------------------------------------
__global__ __launch_bounds__(128) void k2_head(
    const float* __restrict__ S, const float* __restrict__ w2,
    const float* __restrict__ b2, const float* __restrict__ f1w,
    const float* __restrict__ f1b, const float* __restrict__ f2w,
    const float* __restrict__ f2b, float* __restrict__ wgt,
    float* __restrict__ out)
{
  const int b = threadIdx.x;
  if (b >= NB) return;

  float acc[16];
  #pragma unroll
  for (int oc = 0; oc < 16; ++oc) acc[oc] = 0.0f;
  for (int i = 0; i < 150; ++i) {       // i = ic*25 + ky*5 + kx
    float sv = S[b * 150 + i];
    #pragma unroll
    for (int oc = 0; oc < 16; ++oc)
      acc[oc] = fmaf(w2[oc * 150 + i], sv, acc[oc]);  // w2 uniform -> scalar
  }
  const float inv = 1.0f / (106.0f * 106.0f);
  float br[16];
  #pragma unroll
  for (int oc = 0; oc < 16; ++oc) br[oc] = b2[oc] + acc[oc] * inv;

  float h[8];
  #pragma unroll
  for (int j = 0; j < 8; ++j) {
    float t = f1b[j];
    #pragma unroll
    for (int oc = 0; oc < 16; ++oc) t = fmaf(br[oc], f1w[j * 16 + oc], t);
    h[j] = fmaxf(t, 0.0f);
  }
  #pragma unroll
  for (int k = 0; k < 2; ++k) {
    float t = f2b[k];
    #pragma unroll
    for (int j = 0; j < 8; ++j) t = fmaf(h[j], f2w[k * 8 + j], t);
    float w = 2.0f / (1.0f + expf(-t));   // sigmoid * ALPHA
    wgt[2 * b + k] = w;
    out[2 * b + k] = w;                   // output 0: weight [128,2]
  }
}

// ---------------------------------------------------------------------------
// Kernel 3: grid_sample(border, bilinear, align_corners=False) + 10x10 avgpool.
// Block = (h, b); 256 threads; thread (j, wbin) owns output col wbin,
// sample rows {j, j+8}, 10 sample cols. LDS reduce over the 8 j-partials.
// ---------------------------------------------------------------------------
__global__ __launch_bounds__(256) void k3_sample(
    const float* __restrict__ x, const float* __restrict__ lprev,
    const float* __restrict__ g2d, const float* __restrict__ wgt,
    float* __restrict__ out)
{
  const int h = blockIdx.x;     // 0..15
  const int b = blockIdx.y;     // 0..127
  const int tid = threadIdx.x;

  __shared__ float gs[10 * 320 * 2];
  __shared__ float part[8][32][3];

  const float* gsrc = g2d + h * 10 * 320 * 2;   // rows h*10 .. h*10+9, contiguous
  for (int i = tid; i < 6400; i += 256) gs[i] = gsrc[i];

  const float lx = lprev[2 * b],  ly = lprev[2 * b + 1];
  const float wx = wgt[2 * b],    wy = wgt[2 * b + 1];
  __syncthreads();

  const int wbin = tid & 31, j = tid >> 5;
  float sum0 = 0.f, sum1 = 0.f, sum2 = 0.f;
  const float* xb = x + (size_t)b * 3 * IMG * IMG;
  const float* p0 = xb;
  const float* p1 = xb + IMG * IMG;
  const float* p2 = xb + 2 * IMG * IMG;

  for (int jj = j; jj < 10; jj += 8) {
    #pragma unroll
    for (int q = 0; q < 10; ++q) {
      const int widx = wbin * 10 + q;
      float gx = (lx + gs[(jj * 320 + widx) * 2 + 0]) * wx;
      float gy = (ly + gs[(jj * 320 + widx) * 2 + 1]) * wy;
      float ix = ((gx + 1.0f) * 224.0f - 1.0f) * 0.5f;
      float iy = ((gy + 1.0f) * 224.0f - 1.0f) * 0.5f;
      ix = fminf(fmaxf(ix, 0.0f), 223.0f);
      iy = fminf(fmaxf(iy, 0.0f), 223.0f);
      float x0f = floorf(ix), y0f = floorf(iy);
      float fx = ix - x0f, fy = iy - y0f;
      int x0 = (int)x0f, y0 = (int)y0f;
      int x1 = min(x0 + 1, IMG - 1), y1 = min(y0 + 1, IMG - 1);
      float w00 = (1.f - fx) * (1.f - fy), w01 = fx * (1.f - fy);
      float w10 = (1.f - fx) * fy,         w11 = fx * fy;
      int o00 = y0 * IMG + x0, o01 = y0 * IMG + x1;
      int o10 = y1 * IMG + x0, o11 = y1 * IMG + x1;
      sum0 += w00 * p0[o00] + w01 * p0[o01] + w10 * p0[o10] + w11 * p0[o11];
      sum1 += w00 * p1[o00] + w01 * p1[o01] + w10 * p1[o10] + w11 * p1[o11];
      sum2 += w00 * p2[o00] + w01 * p2[o01] + w10 * p2[o10] + w11 * p2[o11];
    }
  }
  part[j][wbin][0] = sum0;
  part[j][wbin][1] = sum1;
  part[j][wbin][2] = sum2;
  __syncthreads();

  if (tid < 96) {
    const int wb = tid & 31, c = tid >> 5;
    float t = 0.f;
    #pragma unroll
    for (int jj = 0; jj < 8; ++jj) t += part[jj][wb][c];
    // output 1: pooled [128,3,16,32], offset by weight's 256 floats
    out[256 + (((b * 3 + c) * 16 + h) * 32) + wb] = t * 0.01f;
  }
}

// ---------------------------------------------------------------------------
extern "C" void kernel_launch(void* const* d_in, const int* in_sizes, int n_in,
                              void* d_out, int out_size, void* d_ws, size_t ws_size,
                              hipStream_t stream) {
  const float* x     = (const float*)d_in[0];   // [128,3,224,224]
  const float* lprev = (const float*)d_in[1];   // [128,2]
  const float* g2d   = (const float*)d_in[2];   // [160,320,2]
  const float* w1    = (const float*)d_in[3];   // [6,3,5,5]
  const float* b1    = (const float*)d_in[4];   // [6]
  const float* w2    = (const float*)d_in[5];   // [16,6,5,5]
  const float* b2    = (const float*)d_in[6];   // [16]
  const float* f1w   = (const float*)d_in[7];   // [8,16]
  const float* f1b   = (const float*)d_in[8];   // [8]
  const float* f2w   = (const float*)d_in[9];   // [2,8]
  const float* f2b   = (const float*)d_in[10];  // [2]
  float* out = (float*)d_out;

  float* S   = (float*)d_ws;          // [128][6][5][5] window sums
  float* wgt = S + NB * 150;          // [128][2]

  hipMemsetAsync(d_ws, 0, NB * 150 * sizeof(float), stream);
  k1_conv1<<<dim3(49, NB), 256, 0, stream>>>(x, w1, b1, S);
  k2_head<<<1, 128, 0, stream>>>(S, w2, b2, f1w, f1b, f2w, f2b, wgt, out);
  k3_sample<<<dim3(16, NB), 256, 0, stream>>>(x, lprev, g2d, wgt, out);
}

// Round 2
// 341.139 us; speedup vs baseline: 1.0567x; 1.0567x over previous
//
#include <hip/hip_runtime.h>
#include <math.h>

#define IMG   224
#define POOL1 110     // maxpooled conv1 map: 110x110
#define NB    128

// ---------------------------------------------------------------------------
// Kernel 1: conv1(3->6,5x5,VALID) + maxpool2x2 fused, then partial
// shifted-window sums into S[b][6][5][5] (for the conv2+global-mean collapse).
// Block = 16x16 pooled outputs for one (b, tile). 7x7 tiles cover 110x110.
// ---------------------------------------------------------------------------
__global__ __launch_bounds__(256) void k1_conv1(
    const float* __restrict__ x, const float* __restrict__ w1,
    const float* __restrict__ b1, float* __restrict__ S)
{
  const int tid = threadIdx.x;
  const int tile = blockIdx.x;          // 0..48
  const int b = blockIdx.y;
  const int t_y = tile / 7, t_x = tile % 7;
  const int P0y = t_y * 16, P0x = t_x * 16;
  const int ty = tid >> 4, tx = tid & 15;
  const int py = P0y + ty, px = P0x + tx;   // pooled coords

  __shared__ float in_t[3][36][37];     // +1 pad on inner dim
  __shared__ float rp[16][6][5];        // row partials for S reduction

  // stage input region rows [2*P0y, 2*P0y+35], cols [2*P0x, 2*P0x+35]
  const int by = 2 * P0y, bx = 2 * P0x;
  for (int idx = tid; idx < 3 * 36 * 36; idx += 256) {
    int c = idx / 1296, r = idx % 1296;
    int row = r / 36, col = r % 36;
    int gy = by + row; if (gy > IMG - 1) gy = IMG - 1;   // clamp (unused lanes)
    int gx = bx + col; if (gx > IMG - 1) gx = IMG - 1;
    in_t[c][row][col] = x[((b * 3 + c) * IMG + gy) * IMG + gx];
  }
  __syncthreads();

  // conv: 2x2 conv positions (one maxpool window) x 6 output channels
  float acc[6][4];
  #pragma unroll
  for (int oc = 0; oc < 6; ++oc) {
    float bb = b1[oc];
    acc[oc][0] = bb; acc[oc][1] = bb; acc[oc][2] = bb; acc[oc][3] = bb;
  }
  #pragma unroll 1
  for (int c = 0; c < 3; ++c) {
    float v[6][6];
    #pragma unroll
    for (int i = 0; i < 6; ++i)
      #pragma unroll
      for (int j = 0; j < 6; ++j)
        v[i][j] = in_t[c][2 * ty + i][2 * tx + j];
    #pragma unroll
    for (int oc = 0; oc < 6; ++oc) {
      #pragma unroll
      for (int ky = 0; ky < 5; ++ky) {
        #pragma unroll
        for (int kx = 0; kx < 5; ++kx) {
          float w = w1[((oc * 3 + c) * 5 + ky) * 5 + kx];  // uniform -> s_load
          acc[oc][0] = fmaf(v[ky][kx],         w, acc[oc][0]);
          acc[oc][1] = fmaf(v[ky][kx + 1],     w, acc[oc][1]);
          acc[oc][2] = fmaf(v[ky + 1][kx],     w, acc[oc][2]);
          acc[oc][3] = fmaf(v[ky + 1][kx + 1], w, acc[oc][3]);
        }
      }
    }
  }

  const bool valid = (py < POOL1) && (px < POOL1);
  float z[6];
  #pragma unroll
  for (int oc = 0; oc < 6; ++oc) {
    float m = fmaxf(fmaxf(acc[oc][0], acc[oc][1]),
                    fmaxf(acc[oc][2], acc[oc][3]));
    z[oc] = valid ? m : 0.0f;
  }

  // Stage A: reduce over tx (16-lane segments) with kx window masks.
  // S[ic,ky,kx] = sum_{py in [ky,ky+105], px in [kx,kx+105]} z[ic,py,px]
  #pragma unroll
  for (int oc = 0; oc < 6; ++oc) {
    #pragma unroll
    for (int kx = 0; kx < 5; ++kx) {
      float vv = (px >= kx && px <= 105 + kx) ? z[oc] : 0.0f;
      vv += __shfl_xor(vv, 1, 16);
      vv += __shfl_xor(vv, 2, 16);
      vv += __shfl_xor(vv, 4, 16);
      vv += __shfl_xor(vv, 8, 16);
      if (tx == 0) rp[ty][oc][kx] = vv;
    }
  }
  __syncthreads();

  // Stage B: reduce over ty with ky masks, one atomicAdd per bin.
  if (tid < 150) {
    int oc = tid / 25, r = tid % 25, ky = r / 5, kx = r % 5;
    float s = 0.f;
    #pragma unroll
    for (int t = 0; t < 16; ++t) {
      int gpy = P0y + t;
      if (gpy >= ky && gpy <= 105 + ky) s += rp[t][oc][kx];
    }
    atomicAdd(&S[b * 150 + tid], s);
  }
}

// ---------------------------------------------------------------------------
// Kernel 2: conv2-as-dot-with-S + global mean + fc1/relu + fc2/sigmoid*2.
// One thread per batch element.
// ---------------------------------------------------------------------------
__global__ __launch_bounds__(128) void k2_head(
    const float* __restrict__ S, const float* __restrict__ w2,
    const float* __restrict__ b2, const float* __restrict__ f1w,
    const float* __restrict__ f1b, const float* __restrict__ f2w,
    const float* __restrict__ f2b, float* __restrict__ wgt,
    float* __restrict__ out)
{
  const int b = threadIdx.x;
  if (b >= NB) return;

  float acc[16];
  #pragma unroll
  for (int oc = 0; oc < 16; ++oc) acc[oc] = 0.0f;
  for (int i = 0; i < 150; ++i) {       // i = ic*25 + ky*5 + kx
    float sv = S[b * 150 + i];
    #pragma unroll
    for (int oc = 0; oc < 16; ++oc)
      acc[oc] = fmaf(w2[oc * 150 + i], sv, acc[oc]);  // w2 uniform -> scalar
  }
  const float inv = 1.0f / (106.0f * 106.0f);
  float br[16];
  #pragma unroll
  for (int oc = 0; oc < 16; ++oc) br[oc] = b2[oc] + acc[oc] * inv;

  float h[8];
  #pragma unroll
  for (int j = 0; j < 8; ++j) {
    float t = f1b[j];
    #pragma unroll
    for (int oc = 0; oc < 16; ++oc) t = fmaf(br[oc], f1w[j * 16 + oc], t);
    h[j] = fmaxf(t, 0.0f);
  }
  #pragma unroll
  for (int k = 0; k < 2; ++k) {
    float t = f2b[k];
    #pragma unroll
    for (int j = 0; j < 8; ++j) t = fmaf(h[j], f2w[k * 8 + j], t);
    float w = 2.0f / (1.0f + expf(-t));   // sigmoid * ALPHA
    wgt[2 * b + k] = w;
    out[2 * b + k] = w;                   // output 0: weight [128,2]
  }
}

// ---------------------------------------------------------------------------
// Kernel 3: grid_sample(border, bilinear, align_corners=False) + 10x10 avgpool.
// Block = (h, b); 256 threads; thread (j, wbin) owns output col wbin and
// samples s=j,j+8,... of the 100-sample (10x10) pool window. No grid staging:
// each grid element is consumed by exactly one thread (L2-resident across b).
// LDS = 3 KB (partials only) -> 8 blocks/CU residency for latency hiding.
// ---------------------------------------------------------------------------
__global__ __launch_bounds__(256) void k3_sample(
    const float* __restrict__ x, const float* __restrict__ lprev,
    const float* __restrict__ g2d, const float* __restrict__ wgt,
    float* __restrict__ out)
{
  const int h = blockIdx.x;     // 0..15
  const int b = blockIdx.y;     // 0..127
  const int tid = threadIdx.x;
  const int wbin = tid & 31, j = tid >> 5;

  __shared__ float part[8][32][3];

  const float lx = lprev[2 * b],  ly = lprev[2 * b + 1];
  const float wx = wgt[2 * b],    wy = wgt[2 * b + 1];

  const float* gbase = g2d + h * 10 * 320 * 2;   // rows h*10 .. h*10+9
  const float* xb = x + (size_t)b * 3 * IMG * IMG;
  const float* p0 = xb;
  const float* p1 = xb + IMG * IMG;
  const float* p2 = xb + 2 * IMG * IMG;

  float sum0 = 0.f, sum1 = 0.f, sum2 = 0.f;
  for (int s = j; s < 100; s += 8) {     // balanced 12-13 samples/thread
    const int jj = s / 10, q = s - jj * 10;
    const int widx = wbin * 10 + q;
    const float2 g = *(const float2*)(gbase + (jj * 320 + widx) * 2);
    float gx = (lx + g.x) * wx;
    float gy = (ly + g.y) * wy;
    float ix = ((gx + 1.0f) * 224.0f - 1.0f) * 0.5f;
    float iy = ((gy + 1.0f) * 224.0f - 1.0f) * 0.5f;
    ix = fminf(fmaxf(ix, 0.0f), 223.0f);
    iy = fminf(fmaxf(iy, 0.0f), 223.0f);
    float x0f = floorf(ix), y0f = floorf(iy);
    float fx = ix - x0f, fy = iy - y0f;
    int x0 = (int)x0f, y0 = (int)y0f;
    int x1 = min(x0 + 1, IMG - 1), y1 = min(y0 + 1, IMG - 1);
    float w00 = (1.f - fx) * (1.f - fy), w01 = fx * (1.f - fy);
    float w10 = (1.f - fx) * fy,         w11 = fx * fy;
    int o00 = y0 * IMG + x0, o01 = y0 * IMG + x1;
    int o10 = y1 * IMG + x0, o11 = y1 * IMG + x1;
    sum0 += w00 * p0[o00] + w01 * p0[o01] + w10 * p0[o10] + w11 * p0[o11];
    sum1 += w00 * p1[o00] + w01 * p1[o01] + w10 * p1[o10] + w11 * p1[o11];
    sum2 += w00 * p2[o00] + w01 * p2[o01] + w10 * p2[o10] + w11 * p2[o11];
  }
  part[j][wbin][0] = sum0;
  part[j][wbin][1] = sum1;
  part[j][wbin][2] = sum2;
  __syncthreads();

  if (tid < 96) {
    const int wb = tid & 31, c = tid >> 5;
    float t = 0.f;
    #pragma unroll
    for (int jj = 0; jj < 8; ++jj) t += part[jj][wb][c];
    // output 1: pooled [128,3,16,32], offset by weight's 256 floats
    out[256 + (((b * 3 + c) * 16 + h) * 32) + wb] = t * 0.01f;
  }
}

// ---------------------------------------------------------------------------
extern "C" void kernel_launch(void* const* d_in, const int* in_sizes, int n_in,
                              void* d_out, int out_size, void* d_ws, size_t ws_size,
                              hipStream_t stream) {
  const float* x     = (const float*)d_in[0];   // [128,3,224,224]
  const float* lprev = (const float*)d_in[1];   // [128,2]
  const float* g2d   = (const float*)d_in[2];   // [160,320,2]
  const float* w1    = (const float*)d_in[3];   // [6,3,5,5]
  const float* b1    = (const float*)d_in[4];   // [6]
  const float* w2    = (const float*)d_in[5];   // [16,6,5,5]
  const float* b2    = (const float*)d_in[6];   // [16]
  const float* f1w   = (const float*)d_in[7];   // [8,16]
  const float* f1b   = (const float*)d_in[8];   // [8]
  const float* f2w   = (const float*)d_in[9];   // [2,8]
  const float* f2b   = (const float*)d_in[10];  // [2]
  float* out = (float*)d_out;

  float* S   = (float*)d_ws;          // [128][6][5][5] window sums
  float* wgt = S + NB * 150;          // [128][2]

  hipMemsetAsync(d_ws, 0, NB * 150 * sizeof(float), stream);
  k1_conv1<<<dim3(49, NB), 256, 0, stream>>>(x, w1, b1, S);
  k2_head<<<1, 128, 0, stream>>>(S, w2, b2, f1w, f1b, f2w, f2b, wgt, out);
  k3_sample<<<dim3(16, NB), 256, 0, stream>>>(x, lprev, g2d, wgt, out);
}

// Round 3
// 313.394 us; speedup vs baseline: 1.1503x; 1.0885x over previous
//
#include <hip/hip_runtime.h>
#include <math.h>

#define IMG   224
#define POOL1 110     // maxpooled conv1 map: 110x110
#define NB    128

// ---------------------------------------------------------------------------
// Kernel 1: conv1(3->6,5x5,VALID) + maxpool2x2 fused, then partial
// shifted-window sums into S[b][6][5][5] (for the conv2+global-mean collapse).
// Block = 16x16 pooled outputs for one (b, tile). 7x7 tiles cover 110x110.
// ---------------------------------------------------------------------------
__global__ __launch_bounds__(256) void k1_conv1(
    const float* __restrict__ x, const float* __restrict__ w1,
    const float* __restrict__ b1, float* __restrict__ S)
{
  const int tid = threadIdx.x;
  const int tile = blockIdx.x;          // 0..48
  const int b = blockIdx.y;
  const int t_y = tile / 7, t_x = tile % 7;
  const int P0y = t_y * 16, P0x = t_x * 16;
  const int ty = tid >> 4, tx = tid & 15;
  const int py = P0y + ty, px = P0x + tx;   // pooled coords

  __shared__ float in_t[3][36][37];     // +1 pad on inner dim
  __shared__ float rp[16][6][5];        // row partials for S reduction

  // stage input region rows [2*P0y, 2*P0y+35], cols [2*P0x, 2*P0x+35]
  const int by = 2 * P0y, bx = 2 * P0x;
  for (int idx = tid; idx < 3 * 36 * 36; idx += 256) {
    int c = idx / 1296, r = idx % 1296;
    int row = r / 36, col = r % 36;
    int gy = by + row; if (gy > IMG - 1) gy = IMG - 1;   // clamp (unused lanes)
    int gx = bx + col; if (gx > IMG - 1) gx = IMG - 1;
    in_t[c][row][col] = x[((b * 3 + c) * IMG + gy) * IMG + gx];
  }
  __syncthreads();

  // conv: 2x2 conv positions (one maxpool window) x 6 output channels
  float acc[6][4];
  #pragma unroll
  for (int oc = 0; oc < 6; ++oc) {
    float bb = b1[oc];
    acc[oc][0] = bb; acc[oc][1] = bb; acc[oc][2] = bb; acc[oc][3] = bb;
  }
  #pragma unroll 1
  for (int c = 0; c < 3; ++c) {
    float v[6][6];
    #pragma unroll
    for (int i = 0; i < 6; ++i)
      #pragma unroll
      for (int j = 0; j < 6; ++j)
        v[i][j] = in_t[c][2 * ty + i][2 * tx + j];
    #pragma unroll
    for (int oc = 0; oc < 6; ++oc) {
      #pragma unroll
      for (int ky = 0; ky < 5; ++ky) {
        #pragma unroll
        for (int kx = 0; kx < 5; ++kx) {
          float w = w1[((oc * 3 + c) * 5 + ky) * 5 + kx];  // uniform -> s_load
          acc[oc][0] = fmaf(v[ky][kx],         w, acc[oc][0]);
          acc[oc][1] = fmaf(v[ky][kx + 1],     w, acc[oc][1]);
          acc[oc][2] = fmaf(v[ky + 1][kx],     w, acc[oc][2]);
          acc[oc][3] = fmaf(v[ky + 1][kx + 1], w, acc[oc][3]);
        }
      }
    }
  }

  const bool valid = (py < POOL1) && (px < POOL1);
  float z[6];
  #pragma unroll
  for (int oc = 0; oc < 6; ++oc) {
    float m = fmaxf(fmaxf(acc[oc][0], acc[oc][1]),
                    fmaxf(acc[oc][2], acc[oc][3]));
    z[oc] = valid ? m : 0.0f;
  }

  // Stage A: reduce over tx (16-lane segments) with kx window masks.
  // S[ic,ky,kx] = sum_{py in [ky,ky+105], px in [kx,kx+105]} z[ic,py,px]
  #pragma unroll
  for (int oc = 0; oc < 6; ++oc) {
    #pragma unroll
    for (int kx = 0; kx < 5; ++kx) {
      float vv = (px >= kx && px <= 105 + kx) ? z[oc] : 0.0f;
      vv += __shfl_xor(vv, 1, 16);
      vv += __shfl_xor(vv, 2, 16);
      vv += __shfl_xor(vv, 4, 16);
      vv += __shfl_xor(vv, 8, 16);
      if (tx == 0) rp[ty][oc][kx] = vv;
    }
  }
  __syncthreads();

  // Stage B: reduce over ty with ky masks, one atomicAdd per bin.
  if (tid < 150) {
    int oc = tid / 25, r = tid % 25, ky = r / 5, kx = r % 5;
    float s = 0.f;
    #pragma unroll
    for (int t = 0; t < 16; ++t) {
      int gpy = P0y + t;
      if (gpy >= ky && gpy <= 105 + ky) s += rp[t][oc][kx];
    }
    atomicAdd(&S[b * 150 + tid], s);
  }
}

// ---------------------------------------------------------------------------
// Kernel 2: conv2-as-dot-with-S + global mean + fc1/relu + fc2/sigmoid*2.
// One thread per batch element.
// ---------------------------------------------------------------------------
__global__ __launch_bounds__(128) void k2_head(
    const float* __restrict__ S, const float* __restrict__ w2,
    const float* __restrict__ b2, const float* __restrict__ f1w,
    const float* __restrict__ f1b, const float* __restrict__ f2w,
    const float* __restrict__ f2b, float* __restrict__ wgt,
    float* __restrict__ out)
{
  const int b = threadIdx.x;
  if (b >= NB) return;

  float acc[16];
  #pragma unroll
  for (int oc = 0; oc < 16; ++oc) acc[oc] = 0.0f;
  for (int i = 0; i < 150; ++i) {       // i = ic*25 + ky*5 + kx
    float sv = S[b * 150 + i];
    #pragma unroll
    for (int oc = 0; oc < 16; ++oc)
      acc[oc] = fmaf(w2[oc * 150 + i], sv, acc[oc]);  // w2 uniform -> scalar
  }
  const float inv = 1.0f / (106.0f * 106.0f);
  float br[16];
  #pragma unroll
  for (int oc = 0; oc < 16; ++oc) br[oc] = b2[oc] + acc[oc] * inv;

  float h[8];
  #pragma unroll
  for (int j = 0; j < 8; ++j) {
    float t = f1b[j];
    #pragma unroll
    for (int oc = 0; oc < 16; ++oc) t = fmaf(br[oc], f1w[j * 16 + oc], t);
    h[j] = fmaxf(t, 0.0f);
  }
  #pragma unroll
  for (int k = 0; k < 2; ++k) {
    float t = f2b[k];
    #pragma unroll
    for (int j = 0; j < 8; ++j) t = fmaf(h[j], f2w[k * 8 + j], t);
    float w = 2.0f / (1.0f + expf(-t));   // sigmoid * ALPHA
    wgt[2 * b + k] = w;
    out[2 * b + k] = w;                   // output 0: weight [128,2]
  }
}

// ---------------------------------------------------------------------------
// Kernel 3: grid_sample(border, bilinear, align_corners=False) + 10x10 avgpool.
// Block = (h, b). Lane index == fine theta index (idx % 320): adjacent lanes
// sample points ~2.2*rho px apart on the same ring arc -> image gathers hit a
// handful of cache lines per wave-load instead of 64 (coalescing is the
// binding constraint per R1 counters). Grid reads are fully coalesced float2.
// Accumulation into the 32 output bins via LDS atomics.
// ---------------------------------------------------------------------------
__global__ __launch_bounds__(256) void k3_sample(
    const float* __restrict__ x, const float* __restrict__ lprev,
    const float* __restrict__ g2d, const float* __restrict__ wgt,
    float* __restrict__ out)
{
  const int h = blockIdx.x;     // 0..15
  const int b = blockIdx.y;     // 0..127
  const int tid = threadIdx.x;

  __shared__ float part[32 * 3];
  if (tid < 96) part[tid] = 0.0f;

  const float lx = lprev[2 * b],  ly = lprev[2 * b + 1];
  const float wx = wgt[2 * b],    wy = wgt[2 * b + 1];

  const float* gbase = g2d + h * 10 * 320 * 2;   // rows h*10 .. h*10+9
  const float* xb = x + (size_t)b * 3 * IMG * IMG;
  const float* p0 = xb;
  const float* p1 = xb + IMG * IMG;
  const float* p2 = xb + 2 * IMG * IMG;
  __syncthreads();

  // 3200 samples: idx = jj*320 + widx; lanes consecutive in widx (theta).
  for (int idx = tid; idx < 3200; idx += 256) {
    const int widx = idx - (idx / 320) * 320;   // idx % 320
    const int wbin = widx / 10;
    const float2 g = *(const float2*)(gbase + idx * 2);
    float gx = (lx + g.x) * wx;
    float gy = (ly + g.y) * wy;
    float ix = ((gx + 1.0f) * 224.0f - 1.0f) * 0.5f;
    float iy = ((gy + 1.0f) * 224.0f - 1.0f) * 0.5f;
    ix = fminf(fmaxf(ix, 0.0f), 223.0f);
    iy = fminf(fmaxf(iy, 0.0f), 223.0f);
    float x0f = floorf(ix), y0f = floorf(iy);
    float fx = ix - x0f, fy = iy - y0f;
    int x0 = (int)x0f, y0 = (int)y0f;
    int x1 = min(x0 + 1, IMG - 1), y1 = min(y0 + 1, IMG - 1);
    float w00 = (1.f - fx) * (1.f - fy), w01 = fx * (1.f - fy);
    float w10 = (1.f - fx) * fy,         w11 = fx * fy;
    int o00 = y0 * IMG + x0, o01 = y0 * IMG + x1;
    int o10 = y1 * IMG + x0, o11 = y1 * IMG + x1;
    float s0 = w00 * p0[o00] + w01 * p0[o01] + w10 * p0[o10] + w11 * p0[o11];
    float s1 = w00 * p1[o00] + w01 * p1[o01] + w10 * p1[o10] + w11 * p1[o11];
    float s2 = w00 * p2[o00] + w01 * p2[o01] + w10 * p2[o10] + w11 * p2[o11];
    atomicAdd(&part[wbin * 3 + 0], s0);
    atomicAdd(&part[wbin * 3 + 1], s1);
    atomicAdd(&part[wbin * 3 + 2], s2);
  }
  __syncthreads();

  if (tid < 96) {
    const int wb = tid / 3, c = tid - wb * 3;
    // output 1: pooled [128,3,16,32], offset by weight's 256 floats
    out[256 + (((b * 3 + c) * 16 + h) * 32) + wb] = part[tid] * 0.01f;
  }
}

// ---------------------------------------------------------------------------
extern "C" void kernel_launch(void* const* d_in, const int* in_sizes, int n_in,
                              void* d_out, int out_size, void* d_ws, size_t ws_size,
                              hipStream_t stream) {
  const float* x     = (const float*)d_in[0];   // [128,3,224,224]
  const float* lprev = (const float*)d_in[1];   // [128,2]
  const float* g2d   = (const float*)d_in[2];   // [160,320,2]
  const float* w1    = (const float*)d_in[3];   // [6,3,5,5]
  const float* b1    = (const float*)d_in[4];   // [6]
  const float* w2    = (const float*)d_in[5];   // [16,6,5,5]
  const float* b2    = (const float*)d_in[6];   // [16]
  const float* f1w   = (const float*)d_in[7];   // [8,16]
  const float* f1b   = (const float*)d_in[8];   // [8]
  const float* f2w   = (const float*)d_in[9];   // [2,8]
  const float* f2b   = (const float*)d_in[10];  // [2]
  float* out = (float*)d_out;

  float* S   = (float*)d_ws;          // [128][6][5][5] window sums
  float* wgt = S + NB * 150;          // [128][2]

  hipMemsetAsync(d_ws, 0, NB * 150 * sizeof(float), stream);
  k1_conv1<<<dim3(49, NB), 256, 0, stream>>>(x, w1, b1, S);
  k2_head<<<1, 128, 0, stream>>>(S, w2, b2, f1w, f1b, f2w, f2b, wgt, out);
  k3_sample<<<dim3(16, NB), 256, 0, stream>>>(x, lprev, g2d, wgt, out);
}

// Round 4
// 306.393 us; speedup vs baseline: 1.1765x; 1.0228x over previous
//
#include <hip/hip_runtime.h>
#include <hip/hip_fp16.h>
#include <math.h>

#define IMG   224
#define PLANE (IMG * IMG)
#define POOL1 110
#define NB    128

// ws layout: S[128*150] f32 | wgt[128*2] f32 | pad | xi[128*224*224] ushort4
#define WS_XI_OFF   81920ull
#define WS_XI_BYTES (128ull * PLANE * 8ull)
#define WS_NEED     (WS_XI_OFF + WS_XI_BYTES)

// ---------------------------------------------------------------------------
// Kernel 0: pack x [128,3,224,224] f32 -> xi [128,224,224,(4)] fp16.
// Channel-interleaved so one bilinear corner = one 8B aligned load.
// ---------------------------------------------------------------------------
__global__ __launch_bounds__(256) void k0_pack(
    const float* __restrict__ x, ushort4* __restrict__ xi)
{
  const int i = blockIdx.x * 256 + threadIdx.x;   // pixel index, 128*50176
  const int b = i / PLANE, p = i - b * PLANE;
  const float* xb = x + (size_t)b * 3 * PLANE;
  ushort4 v;
  v.x = __half_as_ushort(__float2half(xb[p]));
  v.y = __half_as_ushort(__float2half(xb[p + PLANE]));
  v.z = __half_as_ushort(__float2half(xb[p + 2 * PLANE]));
  v.w = 0;
  xi[i] = v;
}

// ---------------------------------------------------------------------------
// Kernel 1: conv1(3->6,5x5,VALID) + maxpool2x2 fused, then partial
// shifted-window sums into S[b][6][5][5] (conv2+global-mean collapse).
// ---------------------------------------------------------------------------
__global__ __launch_bounds__(256) void k1_conv1(
    const float* __restrict__ x, const float* __restrict__ w1,
    const float* __restrict__ b1, float* __restrict__ S)
{
  const int tid = threadIdx.x;
  const int tile = blockIdx.x;          // 0..48
  const int b = blockIdx.y;
  const int t_y = tile / 7, t_x = tile % 7;
  const int P0y = t_y * 16, P0x = t_x * 16;
  const int ty = tid >> 4, tx = tid & 15;
  const int py = P0y + ty, px = P0x + tx;

  __shared__ float in_t[3][36][37];
  __shared__ float rp[16][6][5];

  const int by = 2 * P0y, bx = 2 * P0x;
  for (int idx = tid; idx < 3 * 36 * 36; idx += 256) {
    int c = idx / 1296, r = idx % 1296;
    int row = r / 36, col = r % 36;
    int gy = by + row; if (gy > IMG - 1) gy = IMG - 1;
    int gx = bx + col; if (gx > IMG - 1) gx = IMG - 1;
    in_t[c][row][col] = x[((b * 3 + c) * IMG + gy) * IMG + gx];
  }
  __syncthreads();

  float acc[6][4];
  #pragma unroll
  for (int oc = 0; oc < 6; ++oc) {
    float bb = b1[oc];
    acc[oc][0] = bb; acc[oc][1] = bb; acc[oc][2] = bb; acc[oc][3] = bb;
  }
  #pragma unroll 1
  for (int c = 0; c < 3; ++c) {
    float v[6][6];
    #pragma unroll
    for (int i = 0; i < 6; ++i)
      #pragma unroll
      for (int j = 0; j < 6; ++j)
        v[i][j] = in_t[c][2 * ty + i][2 * tx + j];
    #pragma unroll
    for (int oc = 0; oc < 6; ++oc) {
      #pragma unroll
      for (int ky = 0; ky < 5; ++ky) {
        #pragma unroll
        for (int kx = 0; kx < 5; ++kx) {
          float w = w1[((oc * 3 + c) * 5 + ky) * 5 + kx];
          acc[oc][0] = fmaf(v[ky][kx],         w, acc[oc][0]);
          acc[oc][1] = fmaf(v[ky][kx + 1],     w, acc[oc][1]);
          acc[oc][2] = fmaf(v[ky + 1][kx],     w, acc[oc][2]);
          acc[oc][3] = fmaf(v[ky + 1][kx + 1], w, acc[oc][3]);
        }
      }
    }
  }

  const bool valid = (py < POOL1) && (px < POOL1);
  float z[6];
  #pragma unroll
  for (int oc = 0; oc < 6; ++oc) {
    float m = fmaxf(fmaxf(acc[oc][0], acc[oc][1]),
                    fmaxf(acc[oc][2], acc[oc][3]));
    z[oc] = valid ? m : 0.0f;
  }

  #pragma unroll
  for (int oc = 0; oc < 6; ++oc) {
    #pragma unroll
    for (int kx = 0; kx < 5; ++kx) {
      float vv = (px >= kx && px <= 105 + kx) ? z[oc] : 0.0f;
      vv += __shfl_xor(vv, 1, 16);
      vv += __shfl_xor(vv, 2, 16);
      vv += __shfl_xor(vv, 4, 16);
      vv += __shfl_xor(vv, 8, 16);
      if (tx == 0) rp[ty][oc][kx] = vv;
    }
  }
  __syncthreads();

  if (tid < 150) {
    int oc = tid / 25, r = tid % 25, ky = r / 5, kx = r % 5;
    float s = 0.f;
    #pragma unroll
    for (int t = 0; t < 16; ++t) {
      int gpy = P0y + t;
      if (gpy >= ky && gpy <= 105 + ky) s += rp[t][oc][kx];
    }
    atomicAdd(&S[b * 150 + tid], s);
  }
}

// ---------------------------------------------------------------------------
// Kernel 2: conv2-as-dot-with-S + global mean + fc head.
// ---------------------------------------------------------------------------
__global__ __launch_bounds__(128) void k2_head(
    const float* __restrict__ S, const float* __restrict__ w2,
    const float* __restrict__ b2, const float* __restrict__ f1w,
    const float* __restrict__ f1b, const float* __restrict__ f2w,
    const float* __restrict__ f2b, float* __restrict__ wgt,
    float* __restrict__ out)
{
  const int b = threadIdx.x;
  if (b >= NB) return;

  float acc[16];
  #pragma unroll
  for (int oc = 0; oc < 16; ++oc) acc[oc] = 0.0f;
  for (int i = 0; i < 150; ++i) {
    float sv = S[b * 150 + i];
    #pragma unroll
    for (int oc = 0; oc < 16; ++oc)
      acc[oc] = fmaf(w2[oc * 150 + i], sv, acc[oc]);
  }
  const float inv = 1.0f / (106.0f * 106.0f);
  float br[16];
  #pragma unroll
  for (int oc = 0; oc < 16; ++oc) br[oc] = b2[oc] + acc[oc] * inv;

  float h[8];
  #pragma unroll
  for (int j = 0; j < 8; ++j) {
    float t = f1b[j];
    #pragma unroll
    for (int oc = 0; oc < 16; ++oc) t = fmaf(br[oc], f1w[j * 16 + oc], t);
    h[j] = fmaxf(t, 0.0f);
  }
  #pragma unroll
  for (int k = 0; k < 2; ++k) {
    float t = f2b[k];
    #pragma unroll
    for (int j = 0; j < 8; ++j) t = fmaf(h[j], f2w[k * 8 + j], t);
    float w = 2.0f / (1.0f + expf(-t));
    wgt[2 * b + k] = w;
    out[2 * b + k] = w;
  }
}

// ---------------------------------------------------------------------------
// Kernel 3 (fast): grid sample from channel-interleaved fp16 image.
// Lane = fine theta. 4x 8B corner loads per sample (was 12x 4B).
// ---------------------------------------------------------------------------
__global__ __launch_bounds__(256) void k3_packed(
    const ushort4* __restrict__ xi, const float* __restrict__ lprev,
    const float* __restrict__ g2d, const float* __restrict__ wgt,
    float* __restrict__ out)
{
  const int h = blockIdx.x;     // 0..15
  const int b = blockIdx.y;     // 0..127
  const int tid = threadIdx.x;

  __shared__ float part[32 * 3];
  if (tid < 96) part[tid] = 0.0f;

  const float lx = lprev[2 * b],  ly = lprev[2 * b + 1];
  const float wx = wgt[2 * b],    wy = wgt[2 * b + 1];

  const float* gbase = g2d + h * 10 * 320 * 2;
  const ushort4* xb = xi + (size_t)b * PLANE;
  __syncthreads();

  for (int idx = tid; idx < 3200; idx += 256) {
    const int widx = idx - (idx / 320) * 320;
    const int wbin = widx / 10;
    const float2 g = *(const float2*)(gbase + idx * 2);
    float gx = (lx + g.x) * wx;
    float gy = (ly + g.y) * wy;
    float ix = ((gx + 1.0f) * 224.0f - 1.0f) * 0.5f;
    float iy = ((gy + 1.0f) * 224.0f - 1.0f) * 0.5f;
    ix = fminf(fmaxf(ix, 0.0f), 223.0f);
    iy = fminf(fmaxf(iy, 0.0f), 223.0f);
    float x0f = floorf(ix), y0f = floorf(iy);
    float fx = ix - x0f, fy = iy - y0f;
    int x0 = (int)x0f, y0 = (int)y0f;
    int x1 = min(x0 + 1, IMG - 1), y1 = min(y0 + 1, IMG - 1);
    float w00 = (1.f - fx) * (1.f - fy), w01 = fx * (1.f - fy);
    float w10 = (1.f - fx) * fy,         w11 = fx * fy;
    ushort4 v00 = xb[y0 * IMG + x0];
    ushort4 v01 = xb[y0 * IMG + x1];
    ushort4 v10 = xb[y1 * IMG + x0];
    ushort4 v11 = xb[y1 * IMG + x1];
    float s0 = w00 * __half2float(__ushort_as_half(v00.x))
             + w01 * __half2float(__ushort_as_half(v01.x))
             + w10 * __half2float(__ushort_as_half(v10.x))
             + w11 * __half2float(__ushort_as_half(v11.x));
    float s1 = w00 * __half2float(__ushort_as_half(v00.y))
             + w01 * __half2float(__ushort_as_half(v01.y))
             + w10 * __half2float(__ushort_as_half(v10.y))
             + w11 * __half2float(__ushort_as_half(v11.y));
    float s2 = w00 * __half2float(__ushort_as_half(v00.z))
             + w01 * __half2float(__ushort_as_half(v01.z))
             + w10 * __half2float(__ushort_as_half(v10.z))
             + w11 * __half2float(__ushort_as_half(v11.z));
    atomicAdd(&part[wbin * 3 + 0], s0);
    atomicAdd(&part[wbin * 3 + 1], s1);
    atomicAdd(&part[wbin * 3 + 2], s2);
  }
  __syncthreads();

  if (tid < 96) {
    const int wb = tid / 3, c = tid - wb * 3;
    out[256 + (((b * 3 + c) * 16 + h) * 32) + wb] = part[tid] * 0.01f;
  }
}

// ---------------------------------------------------------------------------
// Kernel 3 (fallback, f32 planar) — used only if ws_size too small for xi.
// ---------------------------------------------------------------------------
__global__ __launch_bounds__(256) void k3_fallback(
    const float* __restrict__ x, const float* __restrict__ lprev,
    const float* __restrict__ g2d, const float* __restrict__ wgt,
    float* __restrict__ out)
{
  const int h = blockIdx.x;
  const int b = blockIdx.y;
  const int tid = threadIdx.x;

  __shared__ float part[32 * 3];
  if (tid < 96) part[tid] = 0.0f;

  const float lx = lprev[2 * b],  ly = lprev[2 * b + 1];
  const float wx = wgt[2 * b],    wy = wgt[2 * b + 1];

  const float* gbase = g2d + h * 10 * 320 * 2;
  const float* xb = x + (size_t)b * 3 * PLANE;
  const float* p0 = xb;
  const float* p1 = xb + PLANE;
  const float* p2 = xb + 2 * PLANE;
  __syncthreads();

  for (int idx = tid; idx < 3200; idx += 256) {
    const int widx = idx - (idx / 320) * 320;
    const int wbin = widx / 10;
    const float2 g = *(const float2*)(gbase + idx * 2);
    float gx = (lx + g.x) * wx;
    float gy = (ly + g.y) * wy;
    float ix = ((gx + 1.0f) * 224.0f - 1.0f) * 0.5f;
    float iy = ((gy + 1.0f) * 224.0f - 1.0f) * 0.5f;
    ix = fminf(fmaxf(ix, 0.0f), 223.0f);
    iy = fminf(fmaxf(iy, 0.0f), 223.0f);
    float x0f = floorf(ix), y0f = floorf(iy);
    float fx = ix - x0f, fy = iy - y0f;
    int x0 = (int)x0f, y0 = (int)y0f;
    int x1 = min(x0 + 1, IMG - 1), y1 = min(y0 + 1, IMG - 1);
    float w00 = (1.f - fx) * (1.f - fy), w01 = fx * (1.f - fy);
    float w10 = (1.f - fx) * fy,         w11 = fx * fy;
    int o00 = y0 * IMG + x0, o01 = y0 * IMG + x1;
    int o10 = y1 * IMG + x0, o11 = y1 * IMG + x1;
    float s0 = w00 * p0[o00] + w01 * p0[o01] + w10 * p0[o10] + w11 * p0[o11];
    float s1 = w00 * p1[o00] + w01 * p1[o01] + w10 * p1[o10] + w11 * p1[o11];
    float s2 = w00 * p2[o00] + w01 * p2[o01] + w10 * p2[o10] + w11 * p2[o11];
    atomicAdd(&part[wbin * 3 + 0], s0);
    atomicAdd(&part[wbin * 3 + 1], s1);
    atomicAdd(&part[wbin * 3 + 2], s2);
  }
  __syncthreads();

  if (tid < 96) {
    const int wb = tid / 3, c = tid - wb * 3;
    out[256 + (((b * 3 + c) * 16 + h) * 32) + wb] = part[tid] * 0.01f;
  }
}

// ---------------------------------------------------------------------------
extern "C" void kernel_launch(void* const* d_in, const int* in_sizes, int n_in,
                              void* d_out, int out_size, void* d_ws, size_t ws_size,
                              hipStream_t stream) {
  const float* x     = (const float*)d_in[0];
  const float* lprev = (const float*)d_in[1];
  const float* g2d   = (const float*)d_in[2];
  const float* w1    = (const float*)d_in[3];
  const float* b1    = (const float*)d_in[4];
  const float* w2    = (const float*)d_in[5];
  const float* b2    = (const float*)d_in[6];
  const float* f1w   = (const float*)d_in[7];
  const float* f1b   = (const float*)d_in[8];
  const float* f2w   = (const float*)d_in[9];
  const float* f2b   = (const float*)d_in[10];
  float* out = (float*)d_out;

  float* S   = (float*)d_ws;                      // [128][150]
  float* wgt = S + NB * 150;                      // [128][2]
  ushort4* xi = (ushort4*)((char*)d_ws + WS_XI_OFF);

  const bool fast = (ws_size >= WS_NEED);

  hipMemsetAsync(d_ws, 0, NB * 150 * sizeof(float), stream);
  if (fast)
    k0_pack<<<NB * PLANE / 256, 256, 0, stream>>>(x, xi);
  k1_conv1<<<dim3(49, NB), 256, 0, stream>>>(x, w1, b1, S);
  k2_head<<<1, 128, 0, stream>>>(S, w2, b2, f1w, f1b, f2w, f2b, wgt, out);
  if (fast)
    k3_packed<<<dim3(16, NB), 256, 0, stream>>>(xi, lprev, g2d, wgt, out);
  else
    k3_fallback<<<dim3(16, NB), 256, 0, stream>>>(x, lprev, g2d, wgt, out);
}

// Round 5
// 300.047 us; speedup vs baseline: 1.2014x; 1.0211x over previous
//
#include <hip/hip_runtime.h>
#include <hip/hip_fp16.h>
#include <math.h>

#define IMG   224
#define PLANE (IMG * IMG)
#define POOL1 110
#define NB    128

// ws layout: S[128*150] f32 | wgt[128*2] f32 | pad | xi[128*224*224] ushort4
#define WS_XI_OFF   81920ull
#define WS_XI_BYTES (128ull * PLANE * 8ull)
#define WS_NEED     (WS_XI_OFF + WS_XI_BYTES)

// ---------------------------------------------------------------------------
// Kernel 0: pack x [128,3,224,224] f32 -> xi [128,224,224,(4)] fp16.
// ---------------------------------------------------------------------------
__global__ __launch_bounds__(256) void k0_pack(
    const float* __restrict__ x, ushort4* __restrict__ xi)
{
  const int i = blockIdx.x * 256 + threadIdx.x;
  const int b = i / PLANE, p = i - b * PLANE;
  const float* xb = x + (size_t)b * 3 * PLANE;
  ushort4 v;
  v.x = __half_as_ushort(__float2half(xb[p]));
  v.y = __half_as_ushort(__float2half(xb[p + PLANE]));
  v.z = __half_as_ushort(__float2half(xb[p + 2 * PLANE]));
  v.w = 0;
  xi[i] = v;
}

// ---------------------------------------------------------------------------
// Kernel 1: conv1(3->6,5x5) + maxpool2x2 + shifted-window sums into S.
// launch_bounds(256,4): 128-VGPR budget so the 6x6 patch + 24 accumulators
// stay register-resident (at the default the compiler chose 52 VGPRs and
// re-read LDS for nearly every FMA -> ds_read-bound, 4.5M bank conflicts).
// ---------------------------------------------------------------------------
__global__ __launch_bounds__(256, 4) void k1_conv1(
    const float* __restrict__ x, const float* __restrict__ w1,
    const float* __restrict__ b1, float* __restrict__ S)
{
  const int tid = threadIdx.x;
  const int tile = blockIdx.x;          // 0..48
  const int b = blockIdx.y;
  const int t_y = tile / 7, t_x = tile % 7;
  const int P0y = t_y * 16, P0x = t_x * 16;
  const int ty = tid >> 4, tx = tid & 15;
  const int py = P0y + ty, px = P0x + tx;

  __shared__ float in_t[3][36][38];     // stride 38: even -> float2-aligned rows
  __shared__ float rp[16][6][5];

  const int by = 2 * P0y, bx = 2 * P0x;
  for (int idx = tid; idx < 3 * 36 * 36; idx += 256) {
    int c = idx / 1296, r = idx % 1296;
    int row = r / 36, col = r % 36;
    int gy = by + row; if (gy > IMG - 1) gy = IMG - 1;
    int gx = bx + col; if (gx > IMG - 1) gx = IMG - 1;
    in_t[c][row][col] = x[((b * 3 + c) * IMG + gy) * IMG + gx];
  }
  __syncthreads();

  float acc[6][4];
  #pragma unroll
  for (int oc = 0; oc < 6; ++oc) {
    float bb = b1[oc];
    acc[oc][0] = bb; acc[oc][1] = bb; acc[oc][2] = bb; acc[oc][3] = bb;
  }
  #pragma unroll 1
  for (int c = 0; c < 3; ++c) {
    // 6x6 patch -> registers, once per channel (18 ds_read_b64)
    float v[6][6];
    const float* rowbase = &in_t[c][2 * ty][2 * tx];
    #pragma unroll
    for (int i = 0; i < 6; ++i) {
      const float2* rp2 = (const float2*)(rowbase + i * 38);
      float2 a = rp2[0], d = rp2[1], e = rp2[2];
      v[i][0] = a.x; v[i][1] = a.y; v[i][2] = d.x;
      v[i][3] = d.y; v[i][4] = e.x; v[i][5] = e.y;
    }
    const float* w1c = w1 + c * 25;     // [oc][c][ky][kx], uniform -> s_load
    #pragma unroll
    for (int oc = 0; oc < 6; ++oc) {
      #pragma unroll
      for (int ky = 0; ky < 5; ++ky) {
        #pragma unroll
        for (int kx = 0; kx < 5; ++kx) {
          float w = w1c[oc * 75 + ky * 5 + kx];
          acc[oc][0] = fmaf(v[ky][kx],         w, acc[oc][0]);
          acc[oc][1] = fmaf(v[ky][kx + 1],     w, acc[oc][1]);
          acc[oc][2] = fmaf(v[ky + 1][kx],     w, acc[oc][2]);
          acc[oc][3] = fmaf(v[ky + 1][kx + 1], w, acc[oc][3]);
        }
      }
    }
  }

  const bool valid = (py < POOL1) && (px < POOL1);
  float z[6];
  #pragma unroll
  for (int oc = 0; oc < 6; ++oc) {
    float m = fmaxf(fmaxf(acc[oc][0], acc[oc][1]),
                    fmaxf(acc[oc][2], acc[oc][3]));
    z[oc] = valid ? m : 0.0f;
  }

  #pragma unroll
  for (int oc = 0; oc < 6; ++oc) {
    #pragma unroll
    for (int kx = 0; kx < 5; ++kx) {
      float vv = (px >= kx && px <= 105 + kx) ? z[oc] : 0.0f;
      vv += __shfl_xor(vv, 1, 16);
      vv += __shfl_xor(vv, 2, 16);
      vv += __shfl_xor(vv, 4, 16);
      vv += __shfl_xor(vv, 8, 16);
      if (tx == 0) rp[ty][oc][kx] = vv;
    }
  }
  __syncthreads();

  if (tid < 150) {
    int oc = tid / 25, r = tid % 25, ky = r / 5, kx = r % 5;
    float s = 0.f;
    #pragma unroll
    for (int t = 0; t < 16; ++t) {
      int gpy = P0y + t;
      if (gpy >= ky && gpy <= 105 + ky) s += rp[t][oc][kx];
    }
    atomicAdd(&S[b * 150 + tid], s);
  }
}

// ---------------------------------------------------------------------------
// Kernel 2: conv2-as-dot-with-S + global mean + fc head.
// ---------------------------------------------------------------------------
__global__ __launch_bounds__(128) void k2_head(
    const float* __restrict__ S, const float* __restrict__ w2,
    const float* __restrict__ b2, const float* __restrict__ f1w,
    const float* __restrict__ f1b, const float* __restrict__ f2w,
    const float* __restrict__ f2b, float* __restrict__ wgt,
    float* __restrict__ out)
{
  const int b = threadIdx.x;
  if (b >= NB) return;

  float acc[16];
  #pragma unroll
  for (int oc = 0; oc < 16; ++oc) acc[oc] = 0.0f;
  for (int i = 0; i < 150; ++i) {
    float sv = S[b * 150 + i];
    #pragma unroll
    for (int oc = 0; oc < 16; ++oc)
      acc[oc] = fmaf(w2[oc * 150 + i], sv, acc[oc]);
  }
  const float inv = 1.0f / (106.0f * 106.0f);
  float br[16];
  #pragma unroll
  for (int oc = 0; oc < 16; ++oc) br[oc] = b2[oc] + acc[oc] * inv;

  float h[8];
  #pragma unroll
  for (int j = 0; j < 8; ++j) {
    float t = f1b[j];
    #pragma unroll
    for (int oc = 0; oc < 16; ++oc) t = fmaf(br[oc], f1w[j * 16 + oc], t);
    h[j] = fmaxf(t, 0.0f);
  }
  #pragma unroll
  for (int k = 0; k < 2; ++k) {
    float t = f2b[k];
    #pragma unroll
    for (int j = 0; j < 8; ++j) t = fmaf(h[j], f2w[k * 8 + j], t);
    float w = 2.0f / (1.0f + expf(-t));
    wgt[2 * b + k] = w;
    out[2 * b + k] = w;
  }
}

// ---------------------------------------------------------------------------
// Kernel 3 (fast): grid sample from channel-interleaved fp16 image.
// ---------------------------------------------------------------------------
__global__ __launch_bounds__(256) void k3_packed(
    const ushort4* __restrict__ xi, const float* __restrict__ lprev,
    const float* __restrict__ g2d, const float* __restrict__ wgt,
    float* __restrict__ out)
{
  const int h = blockIdx.x;     // 0..15
  const int b = blockIdx.y;     // 0..127
  const int tid = threadIdx.x;

  __shared__ float part[32 * 3];
  if (tid < 96) part[tid] = 0.0f;

  const float lx = lprev[2 * b],  ly = lprev[2 * b + 1];
  const float wx = wgt[2 * b],    wy = wgt[2 * b + 1];

  const float* gbase = g2d + h * 10 * 320 * 2;
  const ushort4* xb = xi + (size_t)b * PLANE;
  __syncthreads();

  for (int idx = tid; idx < 3200; idx += 256) {
    const int widx = idx - (idx / 320) * 320;
    const int wbin = widx / 10;
    const float2 g = *(const float2*)(gbase + idx * 2);
    float gx = (lx + g.x) * wx;
    float gy = (ly + g.y) * wy;
    float ix = ((gx + 1.0f) * 224.0f - 1.0f) * 0.5f;
    float iy = ((gy + 1.0f) * 224.0f - 1.0f) * 0.5f;
    ix = fminf(fmaxf(ix, 0.0f), 223.0f);
    iy = fminf(fmaxf(iy, 0.0f), 223.0f);
    float x0f = floorf(ix), y0f = floorf(iy);
    float fx = ix - x0f, fy = iy - y0f;
    int x0 = (int)x0f, y0 = (int)y0f;
    int x1 = min(x0 + 1, IMG - 1), y1 = min(y0 + 1, IMG - 1);
    float w00 = (1.f - fx) * (1.f - fy), w01 = fx * (1.f - fy);
    float w10 = (1.f - fx) * fy,         w11 = fx * fy;
    ushort4 v00 = xb[y0 * IMG + x0];
    ushort4 v01 = xb[y0 * IMG + x1];
    ushort4 v10 = xb[y1 * IMG + x0];
    ushort4 v11 = xb[y1 * IMG + x1];
    float s0 = w00 * __half2float(__ushort_as_half(v00.x))
             + w01 * __half2float(__ushort_as_half(v01.x))
             + w10 * __half2float(__ushort_as_half(v10.x))
             + w11 * __half2float(__ushort_as_half(v11.x));
    float s1 = w00 * __half2float(__ushort_as_half(v00.y))
             + w01 * __half2float(__ushort_as_half(v01.y))
             + w10 * __half2float(__ushort_as_half(v10.y))
             + w11 * __half2float(__ushort_as_half(v11.y));
    float s2 = w00 * __half2float(__ushort_as_half(v00.z))
             + w01 * __half2float(__ushort_as_half(v01.z))
             + w10 * __half2float(__ushort_as_half(v10.z))
             + w11 * __half2float(__ushort_as_half(v11.z));
    atomicAdd(&part[wbin * 3 + 0], s0);
    atomicAdd(&part[wbin * 3 + 1], s1);
    atomicAdd(&part[wbin * 3 + 2], s2);
  }
  __syncthreads();

  if (tid < 96) {
    const int wb = tid / 3, c = tid - wb * 3;
    out[256 + (((b * 3 + c) * 16 + h) * 32) + wb] = part[tid] * 0.01f;
  }
}

// ---------------------------------------------------------------------------
// Kernel 3 (fallback, f32 planar) — used only if ws_size too small for xi.
// ---------------------------------------------------------------------------
__global__ __launch_bounds__(256) void k3_fallback(
    const float* __restrict__ x, const float* __restrict__ lprev,
    const float* __restrict__ g2d, const float* __restrict__ wgt,
    float* __restrict__ out)
{
  const int h = blockIdx.x;
  const int b = blockIdx.y;
  const int tid = threadIdx.x;

  __shared__ float part[32 * 3];
  if (tid < 96) part[tid] = 0.0f;

  const float lx = lprev[2 * b],  ly = lprev[2 * b + 1];
  const float wx = wgt[2 * b],    wy = wgt[2 * b + 1];

  const float* gbase = g2d + h * 10 * 320 * 2;
  const float* xb = x + (size_t)b * 3 * PLANE;
  const float* p0 = xb;
  const float* p1 = xb + PLANE;
  const float* p2 = xb + 2 * PLANE;
  __syncthreads();

  for (int idx = tid; idx < 3200; idx += 256) {
    const int widx = idx - (idx / 320) * 320;
    const int wbin = widx / 10;
    const float2 g = *(const float2*)(gbase + idx * 2);
    float gx = (lx + g.x) * wx;
    float gy = (ly + g.y) * wy;
    float ix = ((gx + 1.0f) * 224.0f - 1.0f) * 0.5f;
    float iy = ((gy + 1.0f) * 224.0f - 1.0f) * 0.5f;
    ix = fminf(fmaxf(ix, 0.0f), 223.0f);
    iy = fminf(fmaxf(iy, 0.0f), 223.0f);
    float x0f = floorf(ix), y0f = floorf(iy);
    float fx = ix - x0f, fy = iy - y0f;
    int x0 = (int)x0f, y0 = (int)y0f;
    int x1 = min(x0 + 1, IMG - 1), y1 = min(y0 + 1, IMG - 1);
    float w00 = (1.f - fx) * (1.f - fy), w01 = fx * (1.f - fy);
    float w10 = (1.f - fx) * fy,         w11 = fx * fy;
    int o00 = y0 * IMG + x0, o01 = y0 * IMG + x1;
    int o10 = y1 * IMG + x0, o11 = y1 * IMG + x1;
    float s0 = w00 * p0[o00] + w01 * p0[o01] + w10 * p0[o10] + w11 * p0[o11];
    float s1 = w00 * p1[o00] + w01 * p1[o01] + w10 * p1[o10] + w11 * p1[o11];
    float s2 = w00 * p2[o00] + w01 * p2[o01] + w10 * p2[o10] + w11 * p2[o11];
    atomicAdd(&part[wbin * 3 + 0], s0);
    atomicAdd(&part[wbin * 3 + 1], s1);
    atomicAdd(&part[wbin * 3 + 2], s2);
  }
  __syncthreads();

  if (tid < 96) {
    const int wb = tid / 3, c = tid - wb * 3;
    out[256 + (((b * 3 + c) * 16 + h) * 32) + wb] = part[tid] * 0.01f;
  }
}

// ---------------------------------------------------------------------------
extern "C" void kernel_launch(void* const* d_in, const int* in_sizes, int n_in,
                              void* d_out, int out_size, void* d_ws, size_t ws_size,
                              hipStream_t stream) {
  const float* x     = (const float*)d_in[0];
  const float* lprev = (const float*)d_in[1];
  const float* g2d   = (const float*)d_in[2];
  const float* w1    = (const float*)d_in[3];
  const float* b1    = (const float*)d_in[4];
  const float* w2    = (const float*)d_in[5];
  const float* b2    = (const float*)d_in[6];
  const float* f1w   = (const float*)d_in[7];
  const float* f1b   = (const float*)d_in[8];
  const float* f2w   = (const float*)d_in[9];
  const float* f2b   = (const float*)d_in[10];
  float* out = (float*)d_out;

  float* S   = (float*)d_ws;                      // [128][150]
  float* wgt = S + NB * 150;                      // [128][2]
  ushort4* xi = (ushort4*)((char*)d_ws + WS_XI_OFF);

  const bool fast = (ws_size >= WS_NEED);

  hipMemsetAsync(d_ws, 0, NB * 150 * sizeof(float), stream);
  if (fast)
    k0_pack<<<NB * PLANE / 256, 256, 0, stream>>>(x, xi);
  k1_conv1<<<dim3(49, NB), 256, 0, stream>>>(x, w1, b1, S);
  k2_head<<<1, 128, 0, stream>>>(S, w2, b2, f1w, f1b, f2w, f2b, wgt, out);
  if (fast)
    k3_packed<<<dim3(16, NB), 256, 0, stream>>>(xi, lprev, g2d, wgt, out);
  else
    k3_fallback<<<dim3(16, NB), 256, 0, stream>>>(x, lprev, g2d, wgt, out);
}